// Round 8
// baseline (177.094 us; speedup 1.0000x reference)
//
#include <hip/hip_runtime.h>

#define Bn 4
#define Qn 128
#define Kn 1024
#define Dn 512   // DQ = DK = DV = 512
#define Hn 256
#define SCALE 2.8853900817779268f   // 2*log2(e): pre-scale proj so tanh uses exp2
#define LOG2E 1.4426950408889634f

typedef __attribute__((ext_vector_type(8))) short short8;   // 8 bf16 = 4 VGPRs
typedef __attribute__((ext_vector_type(4))) float floatx4;  // MFMA C/D

// f32 -> bf16 round-to-nearest-even (inputs are finite normals)
__device__ __forceinline__ unsigned short f2bf(float x) {
    unsigned int u = __float_as_uint(x);
    return (unsigned short)((u + 0x7fffu + ((u >> 16) & 1u)) >> 16);
}

// ---------------------------------------------------------------------------
// Kernel 0: prep. blocks 0..63: LDS-transpose Wq/Wk -> Wt[n][k] bf16 (MFMA
// B-operand = 8 contiguous bf16 of a Wt row). blocks 64..639: f32->bf16
// convert of queries|keys into qk16[4608][512].
// ---------------------------------------------------------------------------
__global__ __launch_bounds__(256) void prep_kernel(
    const float* __restrict__ queries, const float* __restrict__ keys,
    const float* __restrict__ Wq, const float* __restrict__ Wk,
    unsigned short* __restrict__ qk16,
    unsigned short* __restrict__ wtq, unsigned short* __restrict__ wtk)
{
    const int blk = blockIdx.x;
    const int t = threadIdx.x;
    if (blk < 64) {
        __shared__ float s_t[64][68];
        const int wsel = blk >> 5;
        const int tile = blk & 31;
        const int r0 = (tile >> 2) * 64;    // k-offset (512/64 = 8)
        const int c0 = (tile & 3) * 64;     // n-offset (256/64 = 4)
        const float* W = wsel ? Wk : Wq;
        unsigned short* Wt = wsel ? wtk : wtq;
        #pragma unroll
        for (int i = 0; i < 4; ++i) {
            int idx = t + i * 256;
            int row = idx >> 4, c4 = idx & 15;
            float4 v = *(const float4*)(W + (size_t)(r0 + row) * Hn + c0 + c4 * 4);
            s_t[row][c4*4+0] = v.x; s_t[row][c4*4+1] = v.y;
            s_t[row][c4*4+2] = v.z; s_t[row][c4*4+3] = v.w;
        }
        __syncthreads();
        const int n = c0 + (t >> 2);        // output Wt row
        const int seg = t & 3;              // 16-k segment
        unsigned short tmp[16];
        #pragma unroll
        for (int i = 0; i < 16; ++i)
            tmp[i] = f2bf(s_t[seg * 16 + i][t >> 2]);
        uint4* dst = (uint4*)(Wt + (size_t)n * Dn + r0 + seg * 16);
        dst[0] = ((uint4*)tmp)[0];
        dst[1] = ((uint4*)tmp)[1];
    } else {
        const int cblk = blk - 64;          // 576 blocks x 4096 floats
        const float* src = (cblk < 64) ? (queries + (size_t)cblk * 4096)
                                       : (keys + (size_t)(cblk - 64) * 4096);
        const float* s = src + t * 16;
        unsigned short tmp[16];
        #pragma unroll
        for (int i = 0; i < 4; ++i) {
            float4 v = *(const float4*)(s + i * 4);
            tmp[i*4+0] = f2bf(v.x); tmp[i*4+1] = f2bf(v.y);
            tmp[i*4+2] = f2bf(v.z); tmp[i*4+3] = f2bf(v.w);
        }
        uint4* dst = (uint4*)(qk16 + (size_t)cblk * 4096 + t * 16);
        dst[0] = ((uint4*)tmp)[0];
        dst[1] = ((uint4*)tmp)[1];
    }
}

// ---------------------------------------------------------------------------
// Kernel 1: projections via bf16 MFMA (fp32 acc). Block = 64m x 64n, BK=64.
// q-type writes qproj[row][h] directly (score reads it scalar).
// k-type transposes its 64x64 tile in LDS (reusing the staging buffer) and
// writes kprojT[b][h][k] coalesced -- score streams it with lane=k.
// Both outputs pre-scaled by 2*log2(e).
// ---------------------------------------------------------------------------
__global__ __launch_bounds__(256) void proj_mfma_kernel(
    const unsigned short* __restrict__ qk16,
    const unsigned short* __restrict__ wtq,
    const unsigned short* __restrict__ wtk,
    const int* __restrict__ valid_lens,
    float* __restrict__ qproj, float* __restrict__ kprojT)
{
    const int blk = blockIdx.x;             // mt(72) * 4 + nt
    const int nt = blk & 3;
    const int mt = blk >> 2;
    const int n0 = nt * 64;
    int arow0, drow0; const unsigned short* Wt; bool is_q;
    if (mt < 8) {
        arow0 = mt * 64; drow0 = arow0; Wt = wtq; is_q = true;
    } else {
        int r0 = (mt - 8) * 64;
        if ((r0 & 1023) >= valid_lens[r0 >> 10]) return;  // tile fully masked
        arow0 = 512 + r0; drow0 = r0; Wt = wtk; is_q = false;
    }
    const int t = threadIdx.x;
    const int lane = t & 63;
    const int w = t >> 6;

    __shared__ float s_x[64 * 68];          // 17408 B; aliased by staging bufs
    short8* s_a = (short8*)s_x;             // [512] = 8 KB
    short8* s_b = (short8*)(s_x + 2048);    // [512] = 8 KB

    // this thread stages slots t and t+256 of each tile
    int arow[2], brow[2], acol[2];
    #pragma unroll
    for (int i = 0; i < 2; ++i) {
        int s = t + i * 256;
        int grp = s >> 6, l = s & 63;
        int top = grp >> 1, kc = grp & 1;
        arow[i] = arow0 + top * 16 + (l & 15);
        brow[i] = n0 + top * 16 + (l & 15);
        acol[i] = kc * 32 + ((l >> 4) << 3);
    }

    floatx4 z = {0.f, 0.f, 0.f, 0.f};
    floatx4 acc0 = z, acc1 = z, acc2 = z, acc3 = z;

    for (int kt = 0; kt < 8; ++kt) {
        __syncthreads();
        #pragma unroll
        for (int i = 0; i < 2; ++i) {
            s_a[t + i*256] = *(const short8*)(qk16 + (size_t)arow[i] * Dn + kt*64 + acol[i]);
            s_b[t + i*256] = *(const short8*)(Wt   + (size_t)brow[i] * Dn + kt*64 + acol[i]);
        }
        __syncthreads();
        #pragma unroll
        for (int kc = 0; kc < 2; ++kc) {
            short8 a  = s_a[(w*2 + kc)*64 + lane];
            short8 b0 = s_b[(0  + kc)*64 + lane];
            short8 b1 = s_b[(2  + kc)*64 + lane];
            short8 b2 = s_b[(4  + kc)*64 + lane];
            short8 b3 = s_b[(6  + kc)*64 + lane];
            acc0 = __builtin_amdgcn_mfma_f32_16x16x32_bf16(a, b0, acc0, 0, 0, 0);
            acc1 = __builtin_amdgcn_mfma_f32_16x16x32_bf16(a, b1, acc1, 0, 0, 0);
            acc2 = __builtin_amdgcn_mfma_f32_16x16x32_bf16(a, b2, acc2, 0, 0, 0);
            acc3 = __builtin_amdgcn_mfma_f32_16x16x32_bf16(a, b3, acc3, 0, 0, 0);
        }
    }

    floatx4 av[4] = {acc0, acc1, acc2, acc3};
    if (is_q) {
        const int mrow = drow0 + w * 16 + ((lane >> 4) << 2);
        const int ncol = n0 + (lane & 15);
        float* dp = qproj + (size_t)mrow * Hn + ncol;
        #pragma unroll
        for (int g = 0; g < 4; ++g)
            #pragma unroll
            for (int r = 0; r < 4; ++r)
                dp[(size_t)r * Hn + g * 16] = av[g][r] * SCALE;
    } else {
        __syncthreads();                    // staging bufs dead; reuse as s_x
        #pragma unroll
        for (int g = 0; g < 4; ++g) {
            const int n_loc = g * 16 + (lane & 15);
            const int m_base = w * 16 + ((lane >> 4) << 2);
            #pragma unroll
            for (int r = 0; r < 4; ++r)
                s_x[n_loc * 68 + m_base + r] = av[g][r] * SCALE;
        }
        __syncthreads();
        const int bq = drow0 >> 10;
        const int kk0 = drow0 & 1023;
        float* dstT = kprojT + ((size_t)bq * Hn + n0) * Kn + kk0;
        #pragma unroll
        for (int i = 0; i < 4; ++i) {       // 64 h-rows x 16 float4
            int f4 = t + i * 256;
            int row = f4 >> 4, c4 = f4 & 15;
            *(float4*)(dstT + (size_t)row * Kn + c4 * 4) =
                *(const float4*)&s_x[row * 68 + c4 * 4];
        }
    }
}

// ---------------------------------------------------------------------------
// Kernel 2: e = exp(score), max-free. Zero LDS. Block = (b, 4q, 128k);
// wave = 1 q-row, lane owns TWO k-columns (float2 loads: 512B/wave per h,
// 44 VALU cyc per load). Software-pipelined: next 8-h batch of kv prefetched
// into registers while computing the current batch -> L2 latency covered.
// q-row + wv via wave-uniform scalar loads. Grid 1024.
// ---------------------------------------------------------------------------
__global__ __launch_bounds__(256) void score_kernel(
    const float* __restrict__ qproj, const float* __restrict__ kprojT,
    const float* __restrict__ wv, const int* __restrict__ valid_lens,
    float* __restrict__ escores, float* __restrict__ rowsum)
{
    const int blk = blockIdx.x;             // ((b*32 + qt)*8 + kt)
    const int kt = blk & 7;
    const int qt = (blk >> 3) & 31;
    const int b  = blk >> 8;
    const int vlen = valid_lens[b];
    const int k0 = kt * 128;
    if (k0 >= vlen) return;
    const int t = threadIdx.x;
    const int wave = __builtin_amdgcn_readfirstlane(t >> 6);
    const int lane = t & 63;
    const int qrow = qt * 4 + wave;

    const float* qb = qproj + (size_t)(b * Qn + qrow) * Hn;
    const float2* kb = (const float2*)(kprojT + (size_t)b * Hn * Kn + k0) + lane;

    // sum(wv) once per wave (identical in all lanes after butterfly)
    float sumw = wv[lane] + wv[lane + 64] + wv[lane + 128] + wv[lane + 192];
    #pragma unroll
    for (int off = 32; off; off >>= 1)
        sumw += __shfl_xor(sumw, off, 64);

    float acc0 = 0.f, acc1 = 0.f;
    float2 kv[8];
    #pragma unroll
    for (int i = 0; i < 8; ++i)             // preload batch 0
        kv[i] = kb[(size_t)i * (Kn / 2)];

    for (int hb = 0; hb < Hn; hb += 8) {
        float2 cur[8];
        #pragma unroll
        for (int i = 0; i < 8; ++i) cur[i] = kv[i];
        if (hb + 8 < Hn) {                  // prefetch next batch (overlaps)
            #pragma unroll
            for (int i = 0; i < 8; ++i)
                kv[i] = kb[(size_t)(hb + 8 + i) * (Kn / 2)];
        }
        #pragma unroll
        for (int i = 0; i < 8; ++i) {
            const int h = hb + i;
            const float qv = qb[h];         // uniform -> s_load
            const float wvh = wv[h];        // uniform -> s_load
            acc0 = fmaf(wvh, __builtin_amdgcn_rcpf(1.f + exp2f(qv + cur[i].x)), acc0);
            acc1 = fmaf(wvh, __builtin_amdgcn_rcpf(1.f + exp2f(qv + cur[i].y)), acc1);
        }
    }
    const float s0 = sumw - 2.f * acc0;     // = sum_h wv*tanh(q+k)
    const float s1 = sumw - 2.f * acc1;

    const int k = k0 + 2 * lane;
    float e0 = (k < vlen)     ? exp2f(s0 * LOG2E) : 0.f;
    float e1 = (k + 1 < vlen) ? exp2f(s1 * LOG2E) : 0.f;
    float* ep = escores + (size_t)(b * Qn + qrow) * Kn + k;
    if (k + 1 < vlen) {
        float2 e2; e2.x = e0; e2.y = e1;
        *(float2*)ep = e2;
    } else if (k < vlen) {
        ep[0] = e0;
    }
    float es = e0 + e1;
    #pragma unroll
    for (int off = 32; off; off >>= 1)
        es += __shfl_xor(es, off, 64);
    if (lane == 0)
        atomicAdd(&rowsum[b * Qn + qrow], es);
}

// ---------------------------------------------------------------------------
// Kernel 3: split-k AV partials. Zero LDS: e-rows via wave-uniform loads,
// values coalesced. Masked k contribute 0 (escores memset). 512 blocks.
// ---------------------------------------------------------------------------
__global__ __launch_bounds__(256) void av_kernel(
    const float* __restrict__ escores, const float* __restrict__ values,
    float* __restrict__ parts)
{
    const int blk = blockIdx.x;         // (((b*16+qt)*2+dh)*4+kc)
    const int kc = blk & 3;
    const int dh = (blk >> 2) & 1;
    const int qt = (blk >> 3) & 15;
    const int b  = blk >> 7;
    const int t = threadIdx.x;
    const int q0 = qt * 8, kb = kc * 256, d = dh * 256 + t;

    const int ebase = __builtin_amdgcn_readfirstlane((b * Qn + q0) * Kn + kb);
    const float* vb = values + ((size_t)b * Kn + kb) * Dn + d;

    float acc[8] = {0.f, 0.f, 0.f, 0.f, 0.f, 0.f, 0.f, 0.f};
    #pragma unroll 2
    for (int k = 0; k < 256; k += 4) {
        float v0 = vb[(size_t)(k + 0) * Dn];
        float v1 = vb[(size_t)(k + 1) * Dn];
        float v2 = vb[(size_t)(k + 2) * Dn];
        float v3 = vb[(size_t)(k + 3) * Dn];
        #pragma unroll
        for (int j = 0; j < 8; ++j) {
            float4 e4 = *(const float4*)(escores + ebase + j * Kn + k);
            acc[j] += e4.x * v0 + e4.y * v1 + e4.z * v2 + e4.w * v3;
        }
    }
    float* pp = parts + (size_t)kc * (Bn * Qn * Dn) + (size_t)(b * Qn + q0) * Dn + d;
    #pragma unroll
    for (int j = 0; j < 8; ++j)
        pp[(size_t)j * Dn] = acc[j];
}

// ---------------------------------------------------------------------------
// Kernel 4: out = (sum of 4 partials) * rcp(rowsum[row]).
// ---------------------------------------------------------------------------
__global__ __launch_bounds__(256) void reduce_kernel(
    const float* __restrict__ parts, const float* __restrict__ rowsum,
    float* __restrict__ out)
{
    const int idx = blockIdx.x * 256 + threadIdx.x;   // float4 index, 65536
    const int row = (idx * 4) >> 9;                   // / Dn
    const float inv = __builtin_amdgcn_rcpf(rowsum[row]);
    const float4* p = (const float4*)parts;
    float4 a = p[idx];
    float4 b = p[idx + 65536];
    float4 c = p[idx + 131072];
    float4 d = p[idx + 196608];
    float4 o;
    o.x = (a.x + b.x + c.x + d.x) * inv;
    o.y = (a.y + b.y + c.y + d.y) * inv;
    o.z = (a.z + b.z + c.z + d.z) * inv;
    o.w = (a.w + b.w + c.w + d.w) * inv;
    ((float4*)out)[idx] = o;
}

// ---------------------------------------------------------------------------
extern "C" void kernel_launch(void* const* d_in, const int* in_sizes, int n_in,
                              void* d_out, int out_size, void* d_ws, size_t ws_size,
                              hipStream_t stream) {
    const float* queries    = (const float*)d_in[0];
    const float* keys       = (const float*)d_in[1];
    const float* values     = (const float*)d_in[2];
    const int*   valid_lens = (const int*)  d_in[3];
    const float* Wq         = (const float*)d_in[4];
    const float* Wk         = (const float*)d_in[5];
    const float* wv         = (const float*)d_in[6];
    float* out = (float*)d_out;

    float* qproj   = (float*)d_ws;                    //  131072 f (pre-scaled)
    float* kprojT  = qproj + Bn * Qn * Hn;            // 1048576 f [B][H][K]
    float* escores = kprojT + Bn * Hn * Kn;           //  524288 f
    float* rowsum  = escores + Bn * Qn * Kn;          //     512 f
    float* parts   = rowsum + Bn * Qn;                // 1048576 f
    unsigned short* qk16 = (unsigned short*)(parts + 4 * Bn * Qn * Dn);
    unsigned short* wtq  = qk16 + 4608 * 512;         // Wt_q [256][512] bf16
    unsigned short* wtk  = wtq + 256 * 512;           // Wt_k [256][512] bf16

    hipMemsetAsync(escores, 0, (size_t)(Bn * Qn * Kn + Bn * Qn) * sizeof(float),
                   stream);
    prep_kernel<<<640, 256, 0, stream>>>(queries, keys, Wq, Wk, qk16, wtq, wtk);
    proj_mfma_kernel<<<288, 256, 0, stream>>>(qk16, wtq, wtk, valid_lens,
                                              qproj, kprojT);
    score_kernel<<<1024, 256, 0, stream>>>(qproj, kprojT, wv, valid_lens,
                                           escores, rowsum);
    av_kernel<<<512, 256, 0, stream>>>(escores, values, parts);
    reduce_kernel<<<256, 256, 0, stream>>>(parts, rowsum, out);
}

// Round 9
// 173.310 us; speedup vs baseline: 1.0218x; 1.0218x over previous
//
#include <hip/hip_runtime.h>

#define Bn 4
#define Qn 128
#define Kn 1024
#define Dn 512   // DQ = DK = DV = 512
#define Hn 256
#define SCALE 2.8853900817779268f   // 2*log2(e): pre-scale proj so tanh uses exp2
#define LOG2E 1.4426950408889634f

typedef __attribute__((ext_vector_type(8))) short short8;   // 8 bf16 = 4 VGPRs
typedef __attribute__((ext_vector_type(4))) float floatx4;  // MFMA C/D

// f32 -> bf16 round-to-nearest-even (inputs are finite normals)
__device__ __forceinline__ unsigned short f2bf(float x) {
    unsigned int u = __float_as_uint(x);
    return (unsigned short)((u + 0x7fffu + ((u >> 16) & 1u)) >> 16);
}

// ---------------------------------------------------------------------------
// Kernel 0: prep. blocks 0..63: LDS-transpose Wq/Wk -> Wt[n][k] bf16 (MFMA
// B-operand = 8 contiguous bf16 of a Wt row). blocks 64..639: f32->bf16
// convert of queries|keys into qk16[4608][512].
// ---------------------------------------------------------------------------
__global__ __launch_bounds__(256) void prep_kernel(
    const float* __restrict__ queries, const float* __restrict__ keys,
    const float* __restrict__ Wq, const float* __restrict__ Wk,
    unsigned short* __restrict__ qk16,
    unsigned short* __restrict__ wtq, unsigned short* __restrict__ wtk)
{
    const int blk = blockIdx.x;
    const int t = threadIdx.x;
    if (blk < 64) {
        __shared__ float s_t[64][68];
        const int wsel = blk >> 5;
        const int tile = blk & 31;
        const int r0 = (tile >> 2) * 64;    // k-offset (512/64 = 8)
        const int c0 = (tile & 3) * 64;     // n-offset (256/64 = 4)
        const float* W = wsel ? Wk : Wq;
        unsigned short* Wt = wsel ? wtk : wtq;
        #pragma unroll
        for (int i = 0; i < 4; ++i) {
            int idx = t + i * 256;
            int row = idx >> 4, c4 = idx & 15;
            float4 v = *(const float4*)(W + (size_t)(r0 + row) * Hn + c0 + c4 * 4);
            s_t[row][c4*4+0] = v.x; s_t[row][c4*4+1] = v.y;
            s_t[row][c4*4+2] = v.z; s_t[row][c4*4+3] = v.w;
        }
        __syncthreads();
        const int n = c0 + (t >> 2);        // output Wt row
        const int seg = t & 3;              // 16-k segment
        unsigned short tmp[16];
        #pragma unroll
        for (int i = 0; i < 16; ++i)
            tmp[i] = f2bf(s_t[seg * 16 + i][t >> 2]);
        uint4* dst = (uint4*)(Wt + (size_t)n * Dn + r0 + seg * 16);
        dst[0] = ((uint4*)tmp)[0];
        dst[1] = ((uint4*)tmp)[1];
    } else {
        const int cblk = blk - 64;          // 576 blocks x 4096 floats
        const float* src = (cblk < 64) ? (queries + (size_t)cblk * 4096)
                                       : (keys + (size_t)(cblk - 64) * 4096);
        const float* s = src + t * 16;
        unsigned short tmp[16];
        #pragma unroll
        for (int i = 0; i < 4; ++i) {
            float4 v = *(const float4*)(s + i * 4);
            tmp[i*4+0] = f2bf(v.x); tmp[i*4+1] = f2bf(v.y);
            tmp[i*4+2] = f2bf(v.z); tmp[i*4+3] = f2bf(v.w);
        }
        uint4* dst = (uint4*)(qk16 + (size_t)cblk * 4096 + t * 16);
        dst[0] = ((uint4*)tmp)[0];
        dst[1] = ((uint4*)tmp)[1];
    }
}

// ---------------------------------------------------------------------------
// Kernel 1: projections via bf16 MFMA (fp32 acc). Block = 64m x 64n, BK=64.
// q-type writes qproj[row][h] directly (score reads it scalar).
// k-type transposes its 64x64 tile in LDS (reusing the staging buffer) and
// writes kprojT[b][h][k] coalesced -- score streams it with lane=k.
// Both outputs pre-scaled by 2*log2(e).
// ---------------------------------------------------------------------------
__global__ __launch_bounds__(256) void proj_mfma_kernel(
    const unsigned short* __restrict__ qk16,
    const unsigned short* __restrict__ wtq,
    const unsigned short* __restrict__ wtk,
    const int* __restrict__ valid_lens,
    float* __restrict__ qproj, float* __restrict__ kprojT)
{
    const int blk = blockIdx.x;             // mt(72) * 4 + nt
    const int nt = blk & 3;
    const int mt = blk >> 2;
    const int n0 = nt * 64;
    int arow0, drow0; const unsigned short* Wt; bool is_q;
    if (mt < 8) {
        arow0 = mt * 64; drow0 = arow0; Wt = wtq; is_q = true;
    } else {
        int r0 = (mt - 8) * 64;
        if ((r0 & 1023) >= valid_lens[r0 >> 10]) return;  // tile fully masked
        arow0 = 512 + r0; drow0 = r0; Wt = wtk; is_q = false;
    }
    const int t = threadIdx.x;
    const int lane = t & 63;
    const int w = t >> 6;

    __shared__ float s_x[64 * 68];          // 17408 B; aliased by staging bufs
    short8* s_a = (short8*)s_x;             // [512] = 8 KB
    short8* s_b = (short8*)(s_x + 2048);    // [512] = 8 KB

    // this thread stages slots t and t+256 of each tile
    int arow[2], brow[2], acol[2];
    #pragma unroll
    for (int i = 0; i < 2; ++i) {
        int s = t + i * 256;
        int grp = s >> 6, l = s & 63;
        int top = grp >> 1, kc = grp & 1;
        arow[i] = arow0 + top * 16 + (l & 15);
        brow[i] = n0 + top * 16 + (l & 15);
        acol[i] = kc * 32 + ((l >> 4) << 3);
    }

    floatx4 z = {0.f, 0.f, 0.f, 0.f};
    floatx4 acc0 = z, acc1 = z, acc2 = z, acc3 = z;

    for (int kt = 0; kt < 8; ++kt) {
        __syncthreads();
        #pragma unroll
        for (int i = 0; i < 2; ++i) {
            s_a[t + i*256] = *(const short8*)(qk16 + (size_t)arow[i] * Dn + kt*64 + acol[i]);
            s_b[t + i*256] = *(const short8*)(Wt   + (size_t)brow[i] * Dn + kt*64 + acol[i]);
        }
        __syncthreads();
        #pragma unroll
        for (int kc = 0; kc < 2; ++kc) {
            short8 a  = s_a[(w*2 + kc)*64 + lane];
            short8 b0 = s_b[(0  + kc)*64 + lane];
            short8 b1 = s_b[(2  + kc)*64 + lane];
            short8 b2 = s_b[(4  + kc)*64 + lane];
            short8 b3 = s_b[(6  + kc)*64 + lane];
            acc0 = __builtin_amdgcn_mfma_f32_16x16x32_bf16(a, b0, acc0, 0, 0, 0);
            acc1 = __builtin_amdgcn_mfma_f32_16x16x32_bf16(a, b1, acc1, 0, 0, 0);
            acc2 = __builtin_amdgcn_mfma_f32_16x16x32_bf16(a, b2, acc2, 0, 0, 0);
            acc3 = __builtin_amdgcn_mfma_f32_16x16x32_bf16(a, b3, acc3, 0, 0, 0);
        }
    }

    floatx4 av[4] = {acc0, acc1, acc2, acc3};
    if (is_q) {
        const int mrow = drow0 + w * 16 + ((lane >> 4) << 2);
        const int ncol = n0 + (lane & 15);
        float* dp = qproj + (size_t)mrow * Hn + ncol;
        #pragma unroll
        for (int g = 0; g < 4; ++g)
            #pragma unroll
            for (int r = 0; r < 4; ++r)
                dp[(size_t)r * Hn + g * 16] = av[g][r] * SCALE;
    } else {
        __syncthreads();                    // staging bufs dead; reuse as s_x
        #pragma unroll
        for (int g = 0; g < 4; ++g) {
            const int n_loc = g * 16 + (lane & 15);
            const int m_base = w * 16 + ((lane >> 4) << 2);
            #pragma unroll
            for (int r = 0; r < 4; ++r)
                s_x[n_loc * 68 + m_base + r] = av[g][r] * SCALE;
        }
        __syncthreads();
        const int bq = drow0 >> 10;
        const int kk0 = drow0 & 1023;
        float* dstT = kprojT + ((size_t)bq * Hn + n0) * Kn + kk0;
        #pragma unroll
        for (int i = 0; i < 4; ++i) {       // 64 h-rows x 16 float4
            int f4 = t + i * 256;
            int row = f4 >> 4, c4 = f4 & 15;
            *(float4*)(dstT + (size_t)row * Kn + c4 * 4) =
                *(const float4*)&s_x[row * 68 + c4 * 4];
        }
    }
}

// ---------------------------------------------------------------------------
// Kernel 2: e = exp(score), max-free. Zero LDS. Block = (b, 16q, 64k);
// wave = FOUR q-rows x 64 k (lane = one k). One 256B coalesced load per h
// feeds 4 rows of compute (~88 cyc per load). 8-h register prefetch pinned
// by an asm memory barrier (R7's unpinned version was sunk by the compiler:
// VGPR=28). q-rows + wv via wave-uniform scalar loads. Grid 512.
// ---------------------------------------------------------------------------
__global__ __launch_bounds__(256) void score_kernel(
    const float* __restrict__ qproj, const float* __restrict__ kprojT,
    const float* __restrict__ wv, const int* __restrict__ valid_lens,
    float* __restrict__ escores, float* __restrict__ rowsum)
{
    const int blk = blockIdx.x;             // ((b*8 + qt)*16 + kt)
    const int kt = blk & 15;
    const int qt = (blk >> 4) & 7;
    const int b  = blk >> 7;
    const int vlen = valid_lens[b];
    const int k0 = kt * 64;
    if (k0 >= vlen) return;
    const int t = threadIdx.x;
    const int wave = __builtin_amdgcn_readfirstlane(t >> 6);
    const int lane = t & 63;
    const int qrow0 = qt * 16 + wave * 4;

    const float* qb = qproj + (size_t)(b * Qn + qrow0) * Hn;   // 4 rows
    const float* kb = kprojT + (size_t)b * Hn * Kn + k0 + lane;

    // sum(wv) once per wave (identical in all lanes after butterfly)
    float sumw = wv[lane] + wv[lane + 64] + wv[lane + 128] + wv[lane + 192];
    #pragma unroll
    for (int off = 32; off; off >>= 1)
        sumw += __shfl_xor(sumw, off, 64);

    float acc[4] = {0.f, 0.f, 0.f, 0.f};
    float kv[8];
    #pragma unroll
    for (int i = 0; i < 8; ++i)             // preload batch 0
        kv[i] = kb[(size_t)i * Kn];

    #pragma unroll 1
    for (int hb = 0; hb < Hn; hb += 8) {
        float cur[8];
        #pragma unroll
        for (int i = 0; i < 8; ++i) cur[i] = kv[i];
        if (hb + 8 < Hn) {                  // prefetch next batch
            #pragma unroll
            for (int i = 0; i < 8; ++i)
                kv[i] = kb[(size_t)(hb + 8 + i) * Kn];
        }
        // pin: prefetch loads must issue before the compute below
        asm volatile("" ::: "memory");
        #pragma unroll
        for (int i = 0; i < 8; ++i) {
            const int h = hb + i;
            const float wvh = wv[h];        // uniform -> s_load
            const float q0 = qb[0 * Hn + h];
            const float q1 = qb[1 * Hn + h];
            const float q2 = qb[2 * Hn + h];
            const float q3 = qb[3 * Hn + h];
            acc[0] = fmaf(wvh, __builtin_amdgcn_rcpf(1.f + exp2f(q0 + cur[i])), acc[0]);
            acc[1] = fmaf(wvh, __builtin_amdgcn_rcpf(1.f + exp2f(q1 + cur[i])), acc[1]);
            acc[2] = fmaf(wvh, __builtin_amdgcn_rcpf(1.f + exp2f(q2 + cur[i])), acc[2]);
            acc[3] = fmaf(wvh, __builtin_amdgcn_rcpf(1.f + exp2f(q3 + cur[i])), acc[3]);
        }
    }

    const int k = k0 + lane;
    const bool ok = (k < vlen);
    float* ep = escores + (size_t)(b * Qn + qrow0) * Kn + k;
    #pragma unroll
    for (int r = 0; r < 4; ++r) {
        float s = sumw - 2.f * acc[r];      // = sum_h wv*tanh(q+k)
        float e = ok ? exp2f(s * LOG2E) : 0.f;
        if (ok) ep[(size_t)r * Kn] = e;
        #pragma unroll
        for (int off = 32; off; off >>= 1)
            e += __shfl_xor(e, off, 64);
        if (lane == 0)
            atomicAdd(&rowsum[b * Qn + qrow0 + r], e);
    }
}

// ---------------------------------------------------------------------------
// Kernel 3: split-k AV partials. Zero LDS: e-rows via wave-uniform loads,
// values coalesced. Masked k contribute 0 (escores memset). 512 blocks.
// ---------------------------------------------------------------------------
__global__ __launch_bounds__(256) void av_kernel(
    const float* __restrict__ escores, const float* __restrict__ values,
    float* __restrict__ parts)
{
    const int blk = blockIdx.x;         // (((b*16+qt)*2+dh)*4+kc)
    const int kc = blk & 3;
    const int dh = (blk >> 2) & 1;
    const int qt = (blk >> 3) & 15;
    const int b  = blk >> 7;
    const int t = threadIdx.x;
    const int q0 = qt * 8, kb = kc * 256, d = dh * 256 + t;

    const int ebase = __builtin_amdgcn_readfirstlane((b * Qn + q0) * Kn + kb);
    const float* vb = values + ((size_t)b * Kn + kb) * Dn + d;

    float acc[8] = {0.f, 0.f, 0.f, 0.f, 0.f, 0.f, 0.f, 0.f};
    #pragma unroll 2
    for (int k = 0; k < 256; k += 4) {
        float v0 = vb[(size_t)(k + 0) * Dn];
        float v1 = vb[(size_t)(k + 1) * Dn];
        float v2 = vb[(size_t)(k + 2) * Dn];
        float v3 = vb[(size_t)(k + 3) * Dn];
        #pragma unroll
        for (int j = 0; j < 8; ++j) {
            float4 e4 = *(const float4*)(escores + ebase + j * Kn + k);
            acc[j] += e4.x * v0 + e4.y * v1 + e4.z * v2 + e4.w * v3;
        }
    }
    float* pp = parts + (size_t)kc * (Bn * Qn * Dn) + (size_t)(b * Qn + q0) * Dn + d;
    #pragma unroll
    for (int j = 0; j < 8; ++j)
        pp[(size_t)j * Dn] = acc[j];
}

// ---------------------------------------------------------------------------
// Kernel 4: out = (sum of 4 partials) * rcp(rowsum[row]).
// ---------------------------------------------------------------------------
__global__ __launch_bounds__(256) void reduce_kernel(
    const float* __restrict__ parts, const float* __restrict__ rowsum,
    float* __restrict__ out)
{
    const int idx = blockIdx.x * 256 + threadIdx.x;   // float4 index, 65536
    const int row = (idx * 4) >> 9;                   // / Dn
    const float inv = __builtin_amdgcn_rcpf(rowsum[row]);
    const float4* p = (const float4*)parts;
    float4 a = p[idx];
    float4 b = p[idx + 65536];
    float4 c = p[idx + 131072];
    float4 d = p[idx + 196608];
    float4 o;
    o.x = (a.x + b.x + c.x + d.x) * inv;
    o.y = (a.y + b.y + c.y + d.y) * inv;
    o.z = (a.z + b.z + c.z + d.z) * inv;
    o.w = (a.w + b.w + c.w + d.w) * inv;
    ((float4*)out)[idx] = o;
}

// ---------------------------------------------------------------------------
extern "C" void kernel_launch(void* const* d_in, const int* in_sizes, int n_in,
                              void* d_out, int out_size, void* d_ws, size_t ws_size,
                              hipStream_t stream) {
    const float* queries    = (const float*)d_in[0];
    const float* keys       = (const float*)d_in[1];
    const float* values     = (const float*)d_in[2];
    const int*   valid_lens = (const int*)  d_in[3];
    const float* Wq         = (const float*)d_in[4];
    const float* Wk         = (const float*)d_in[5];
    const float* wv         = (const float*)d_in[6];
    float* out = (float*)d_out;

    float* qproj   = (float*)d_ws;                    //  131072 f (pre-scaled)
    float* kprojT  = qproj + Bn * Qn * Hn;            // 1048576 f [B][H][K]
    float* escores = kprojT + Bn * Hn * Kn;           //  524288 f
    float* rowsum  = escores + Bn * Qn * Kn;          //     512 f
    float* parts   = rowsum + Bn * Qn;                // 1048576 f
    unsigned short* qk16 = (unsigned short*)(parts + 4 * Bn * Qn * Dn);
    unsigned short* wtq  = qk16 + 4608 * 512;         // Wt_q [256][512] bf16
    unsigned short* wtk  = wtq + 256 * 512;           // Wt_k [256][512] bf16

    hipMemsetAsync(escores, 0, (size_t)(Bn * Qn * Kn + Bn * Qn) * sizeof(float),
                   stream);
    prep_kernel<<<640, 256, 0, stream>>>(queries, keys, Wq, Wk, qk16, wtq, wtk);
    proj_mfma_kernel<<<288, 256, 0, stream>>>(qk16, wtq, wtk, valid_lens,
                                              qproj, kprojT);
    score_kernel<<<512, 256, 0, stream>>>(qproj, kprojT, wv, valid_lens,
                                          escores, rowsum);
    av_kernel<<<512, 256, 0, stream>>>(escores, values, parts);
    reduce_kernel<<<256, 256, 0, stream>>>(parts, rowsum, out);
}